// Round 1
// baseline (116.571 us; speedup 1.0000x reference)
//
#include <hip/hip_runtime.h>
#include <math.h>

// FSQ: x (64,32768,4) f32 -> z (level-major transposed layout) + code.
// N rows, D=4 dims, LEVELS = [8,5,5,5].
#define N_ROWS 2097152  // 64*32768
#define NPT 4           // rows per thread

// Levels replicating np.linspace(-1,1,n,dtype=float32): computed in double,
// cast to f32; endpoint set exactly.
__device__ __constant__ float L8[8] = {
    -1.0f,
    (float)(1.0 * (2.0 / 7.0) - 1.0),
    (float)(2.0 * (2.0 / 7.0) - 1.0),
    (float)(3.0 * (2.0 / 7.0) - 1.0),
    (float)(4.0 * (2.0 / 7.0) - 1.0),
    (float)(5.0 * (2.0 / 7.0) - 1.0),
    (float)(6.0 * (2.0 / 7.0) - 1.0),
    1.0f};
__device__ __constant__ float L5[5] = {-1.0f, -0.5f, 0.0f, 0.5f, 1.0f};

// Exact replication of np argmin over |lv[j]-xi| (first-occurrence ties).
template <int NLEV>
__device__ inline void quant(float xi, const float* __restrict__ lv,
                             float& st, int& idx) {
    float best = fabsf(lv[0] - xi);
    int bi = 0;
#pragma unroll
    for (int j = 1; j < NLEV; ++j) {
        float d = fabsf(lv[j] - xi);
        if (d < best) { best = d; bi = j; }
    }
    float q = lv[bi];
    st = xi + (q - xi);  // same op order as reference (f32)
    idx = bi;
}

__global__ __launch_bounds__(256) void fsq_kernel(const float* __restrict__ x,
                                                  float* __restrict__ out) {
    const int t = blockIdx.x * blockDim.x + threadIdx.x;  // 0 .. N_ROWS/NPT-1
    if (t >= N_ROWS / NPT) return;
    const long long n0 = (long long)t * NPT;

    float z0[NPT], z1[NPT], z2[NPT], z3[NPT], cf[NPT];

#pragma unroll
    for (int j = 0; j < NPT; ++j) {
        // coalesced 16B read: row n0+j
        const float4 xv = reinterpret_cast<const float4*>(x)[n0 + j];
        // tanh in double (near-correctly-rounded f32 on cast) to minimize
        // argmin boundary flips vs numpy's f32 tanh.
        float xi0 = (float)tanh((double)xv.x);
        float xi1 = (float)tanh((double)xv.y);
        float xi2 = (float)tanh((double)xv.z);
        float xi3 = (float)tanh((double)xv.w);
        int i0, i1, i2, i3;
        quant<8>(xi0, L8, z0[j], i0);
        quant<5>(xi1, L5, z1[j], i1);
        quant<5>(xi2, L5, z2[j], i2);
        quant<5>(xi3, L5, z3[j], i3);
        cf[j] = (float)(i0 + 8 * i1 + 40 * i2 + 200 * i3);
    }

    // z is level-major: out[l*N + n]; 16B coalesced stores per stream.
    float4* o0 = reinterpret_cast<float4*>(out + 0ll * N_ROWS);
    float4* o1 = reinterpret_cast<float4*>(out + 1ll * N_ROWS);
    float4* o2 = reinterpret_cast<float4*>(out + 2ll * N_ROWS);
    float4* o3 = reinterpret_cast<float4*>(out + 3ll * N_ROWS);
    float4* oc = reinterpret_cast<float4*>(out + 4ll * N_ROWS);
    o0[t] = make_float4(z0[0], z0[1], z0[2], z0[3]);
    o1[t] = make_float4(z1[0], z1[1], z1[2], z1[3]);
    o2[t] = make_float4(z2[0], z2[1], z2[2], z2[3]);
    o3[t] = make_float4(z3[0], z3[1], z3[2], z3[3]);
    oc[t] = make_float4(cf[0], cf[1], cf[2], cf[3]);
}

extern "C" void kernel_launch(void* const* d_in, const int* in_sizes, int n_in,
                              void* d_out, int out_size, void* d_ws, size_t ws_size,
                              hipStream_t stream) {
    const float* x = (const float*)d_in[0];
    float* out = (float*)d_out;
    const int threads = 256;
    const int total = N_ROWS / NPT;              // 524288 threads
    const int blocks = (total + threads - 1) / threads;  // 2048
    fsq_kernel<<<blocks, threads, 0, stream>>>(x, out);
}

// Round 2
// 88.033 us; speedup vs baseline: 1.3242x; 1.3242x over previous
//
#include <hip/hip_runtime.h>
#include <math.h>

// FSQ: x (64,32768,4) f32 -> z (level-major transposed layout) + code.
// LEVELS = [8,5,5,5], N rows of D=4.
#define N_ROWS 2097152  // 64*32768
#define NPT 4           // rows per thread

// Levels replicating np.linspace(-1,1,n,dtype=float32).
__device__ __constant__ float L8[8] = {
    -1.0f,
    (float)(1.0 * (2.0 / 7.0) - 1.0),
    (float)(2.0 * (2.0 / 7.0) - 1.0),
    (float)(3.0 * (2.0 / 7.0) - 1.0),
    (float)(4.0 * (2.0 / 7.0) - 1.0),
    (float)(5.0 * (2.0 / 7.0) - 1.0),
    (float)(6.0 * (2.0 / 7.0) - 1.0),
    1.0f};
__device__ __constant__ float L5[5] = {-1.0f, -0.5f, 0.0f, 0.5f, 1.0f};

// Exact slow-path quant: replicate np argmin |lv[j]-xi| (first-occurrence).
template <int NLEV>
__device__ inline void quant_exact(float xi, const float* __restrict__ lv,
                                   float& st, int& idx) {
    float best = fabsf(lv[0] - xi);
    int bi = 0;
#pragma unroll
    for (int j = 1; j < NLEV; ++j) {
        float d = fabsf(lv[j] - xi);
        if (d < best) { best = d; bi = j; }
    }
    float q = lv[bi];
    st = xi + (q - xi);  // reference op order
    idx = bi;
}

// Fast f32 tanh: 1 - 2/(e^{2x}+1). Abs error <= ~5e-7 on output in [-1,1].
__device__ __forceinline__ float fast_tanh(float x) {
    float e = __expf(2.0f * x);
    return 1.0f - 2.0f / (e + 1.0f);
}

// Units-distance from v to nearest decision boundary (half-integers of v).
// EPS_U = 5e-5 units covers fast-tanh error (5e-7 * s<=3.5 = 1.75e-6 units)
// with >25x margin, plus f32-level midpoint shift (~1e-7).
#define EPS_U 5e-5f

__global__ __launch_bounds__(256) void fsq_kernel(const float* __restrict__ x,
                                                  float* __restrict__ out) {
    const int t = blockIdx.x * blockDim.x + threadIdx.x;
    if (t >= N_ROWS / NPT) return;
    const long long n0 = (long long)t * NPT;

    float z0[NPT], z1[NPT], z2[NPT], z3[NPT], cf[NPT];
    float4 xin[NPT];

#pragma unroll
    for (int j = 0; j < NPT; ++j)
        xin[j] = reinterpret_cast<const float4*>(x)[n0 + j];

#pragma unroll
    for (int j = 0; j < NPT; ++j) {
        const float4 xv = xin[j];
        float xi0 = fast_tanh(xv.x);
        float xi1 = fast_tanh(xv.y);
        float xi2 = fast_tanh(xv.z);
        float xi3 = fast_tanh(xv.w);

        // dim 0: n=8, s=3.5
        float v0 = (xi0 + 1.0f) * 3.5f;
        float k0f = rintf(v0);
        float g0 = 0.5f - fabsf(v0 - k0f);
        int i0 = (int)k0f;
        // bit-match the L8 table: same double formula it was built from
        float q0 = (float)((double)i0 * (2.0 / 7.0) - 1.0);

        // dims 1-3: n=5, s=2
        float v1 = (xi1 + 1.0f) * 2.0f;
        float k1f = rintf(v1);
        float g1 = 0.5f - fabsf(v1 - k1f);
        int i1 = (int)k1f;
        float q1 = fmaf(k1f, 0.5f, -1.0f);  // exact in f32

        float v2 = (xi2 + 1.0f) * 2.0f;
        float k2f = rintf(v2);
        float g2 = 0.5f - fabsf(v2 - k2f);
        int i2 = (int)k2f;
        float q2 = fmaf(k2f, 0.5f, -1.0f);

        float v3 = (xi3 + 1.0f) * 2.0f;
        float k3f = rintf(v3);
        float g3 = 0.5f - fabsf(v3 - k3f);
        int i3 = (int)k3f;
        float q3 = fmaf(k3f, 0.5f, -1.0f);

        bool need_slow = (g0 < EPS_U) | (g1 < EPS_U) | (g2 < EPS_U) | (g3 < EPS_U);
        if (need_slow) {
            // Exact reference path: f64 tanh (rounds to numpy f32 tanh,
            // verified absmax 0.0 in R1) + exact argmin with f32 levels.
            xi0 = (float)tanh((double)xv.x);
            xi1 = (float)tanh((double)xv.y);
            xi2 = (float)tanh((double)xv.z);
            xi3 = (float)tanh((double)xv.w);
            quant_exact<8>(xi0, L8, q0, i0);
            quant_exact<5>(xi1, L5, q1, i1);
            quant_exact<5>(xi2, L5, q2, i2);
            quant_exact<5>(xi3, L5, q3, i3);
        }

        z0[j] = q0;
        z1[j] = q1;
        z2[j] = q2;
        z3[j] = q3;
        cf[j] = (float)(i0 + 8 * i1 + 40 * i2 + 200 * i3);
    }

    float4* o0 = reinterpret_cast<float4*>(out + 0ll * N_ROWS);
    float4* o1 = reinterpret_cast<float4*>(out + 1ll * N_ROWS);
    float4* o2 = reinterpret_cast<float4*>(out + 2ll * N_ROWS);
    float4* o3 = reinterpret_cast<float4*>(out + 3ll * N_ROWS);
    float4* oc = reinterpret_cast<float4*>(out + 4ll * N_ROWS);
    o0[t] = make_float4(z0[0], z0[1], z0[2], z0[3]);
    o1[t] = make_float4(z1[0], z1[1], z1[2], z1[3]);
    o2[t] = make_float4(z2[0], z2[1], z2[2], z2[3]);
    o3[t] = make_float4(z3[0], z3[1], z3[2], z3[3]);
    oc[t] = make_float4(cf[0], cf[1], cf[2], cf[3]);
}

extern "C" void kernel_launch(void* const* d_in, const int* in_sizes, int n_in,
                              void* d_out, int out_size, void* d_ws, size_t ws_size,
                              hipStream_t stream) {
    const float* x = (const float*)d_in[0];
    float* out = (float*)d_out;
    const int threads = 256;
    const int total = N_ROWS / NPT;
    const int blocks = (total + threads - 1) / threads;
    fsq_kernel<<<blocks, threads, 0, stream>>>(x, out);
}

// Round 3
// 83.993 us; speedup vs baseline: 1.3879x; 1.0481x over previous
//
#include <hip/hip_runtime.h>
#include <math.h>

// FSQ: x (64,32768,4) f32 -> z (level-major transposed layout) + code.
// LEVELS = [8,5,5,5], N rows of D=4.
#define N_ROWS 2097152  // 64*32768
#define NPT 4           // rows per thread (float4-coalesced stores need 4)

// Levels replicating np.linspace(-1,1,n,dtype=float32).
__device__ __constant__ float L8[8] = {
    -1.0f,
    (float)(1.0 * (2.0 / 7.0) - 1.0),
    (float)(2.0 * (2.0 / 7.0) - 1.0),
    (float)(3.0 * (2.0 / 7.0) - 1.0),
    (float)(4.0 * (2.0 / 7.0) - 1.0),
    (float)(5.0 * (2.0 / 7.0) - 1.0),
    (float)(6.0 * (2.0 / 7.0) - 1.0),
    1.0f};
__device__ __constant__ float L5[5] = {-1.0f, -0.5f, 0.0f, 0.5f, 1.0f};

// Exact slow-path quant: replicate np argmin |lv[j]-xi| (first-occurrence).
template <int NLEV>
__device__ inline void quant_exact(float xi, const float* __restrict__ lv,
                                   int& idx) {
    float best = fabsf(lv[0] - xi);
    int bi = 0;
#pragma unroll
    for (int j = 1; j < NLEV; ++j) {
        float d = fabsf(lv[j] - xi);
        if (d < best) { best = d; bi = j; }
    }
    idx = bi;
}

// Fast tanh: t = 1 - 2*rcp(exp2(x*2/ln2) + 1).
// v_exp_f32 (~1 ulp) + v_rcp_f32 (~1 ulp) -> abs output error <= ~1e-6.
__device__ __forceinline__ float fast_tanh(float x) {
    float e = __builtin_amdgcn_exp2f(x * 2.88539008177792681472f);  // 2/ln2
    return fmaf(-2.0f, __builtin_amdgcn_rcpf(e + 1.0f), 1.0f);
}

// Guard: |v - rint(v)| > 0.5 - EPS_U  => too close to a decision boundary,
// take the exact path. EPS_U = 5e-5 units vs fast-path error <= 3.5e-6 units
// (14x margin), so off-guard indices are provably identical to the reference.
#define GTHR (0.5f - 5e-5f)

__global__ __launch_bounds__(256) void fsq_kernel(const float* __restrict__ x,
                                                  float* __restrict__ out) {
    const int t = blockIdx.x * blockDim.x + threadIdx.x;
    if (t >= N_ROWS / NPT) return;
    const long long n0 = (long long)t * NPT;

    float z0[NPT], z1[NPT], z2[NPT], z3[NPT], cf[NPT];
    float4 xin[NPT];

#pragma unroll
    for (int j = 0; j < NPT; ++j)
        xin[j] = reinterpret_cast<const float4*>(x)[n0 + j];

#pragma unroll
    for (int j = 0; j < NPT; ++j) {
        const float4 xv = xin[j];
        float t0 = fast_tanh(xv.x);
        float t1 = fast_tanh(xv.y);
        float t2 = fast_tanh(xv.z);
        float t3 = fast_tanh(xv.w);

        // v = (t+1)*s ; k = rint(v) ; d = v-k (boundary distance)
        float v0 = fmaf(t0, 3.5f, 3.5f);
        float v1 = fmaf(t1, 2.0f, 2.0f);
        float v2 = fmaf(t2, 2.0f, 2.0f);
        float v3 = fmaf(t3, 2.0f, 2.0f);
        float k0 = rintf(v0);
        float k1 = rintf(v1);
        float k2 = rintf(v2);
        float k3 = rintf(v3);
        float m = fmaxf(fmaxf(fabsf(v0 - k0), fabsf(v1 - k1)),
                        fmaxf(fabsf(v2 - k2), fabsf(v3 - k3)));

        if (m > GTHR) {
            // Exact reference path: f64 tanh (rounds to numpy f32 tanh,
            // verified absmax 0.0 in R1) + exact argmin with f32 levels.
            float xi0 = (float)tanh((double)xv.x);
            float xi1 = (float)tanh((double)xv.y);
            float xi2 = (float)tanh((double)xv.z);
            float xi3 = (float)tanh((double)xv.w);
            int i0, i1, i2, i3;
            quant_exact<8>(xi0, L8, i0);
            quant_exact<5>(xi1, L5, i1);
            quant_exact<5>(xi2, L5, i2);
            quant_exact<5>(xi3, L5, i3);
            k0 = (float)i0; k1 = (float)i1; k2 = (float)i2; k3 = (float)i3;
        }

        // q values: dim0 bit-matches L8 via the same double formula;
        // dims 1-3 exact in f32. (st = xi + (q - xi) == q exactly here is
        // within 1 ulp of the reference's f32 st.)
        z0[j] = (float)((double)k0 * (2.0 / 7.0) - 1.0);
        z1[j] = fmaf(k1, 0.5f, -1.0f);
        z2[j] = fmaf(k2, 0.5f, -1.0f);
        z3[j] = fmaf(k3, 0.5f, -1.0f);
        // code = i0 + 8*i1 + 40*i2 + 200*i3 (integers <= 999, exact in f32)
        cf[j] = fmaf(200.0f, k3, fmaf(40.0f, k2, fmaf(8.0f, k1, k0)));
    }

    float4* o0 = reinterpret_cast<float4*>(out + 0ll * N_ROWS);
    float4* o1 = reinterpret_cast<float4*>(out + 1ll * N_ROWS);
    float4* o2 = reinterpret_cast<float4*>(out + 2ll * N_ROWS);
    float4* o3 = reinterpret_cast<float4*>(out + 3ll * N_ROWS);
    float4* oc = reinterpret_cast<float4*>(out + 4ll * N_ROWS);
    o0[t] = make_float4(z0[0], z0[1], z0[2], z0[3]);
    o1[t] = make_float4(z1[0], z1[1], z1[2], z1[3]);
    o2[t] = make_float4(z2[0], z2[1], z2[2], z2[3]);
    o3[t] = make_float4(z3[0], z3[1], z3[2], z3[3]);
    oc[t] = make_float4(cf[0], cf[1], cf[2], cf[3]);
}

extern "C" void kernel_launch(void* const* d_in, const int* in_sizes, int n_in,
                              void* d_out, int out_size, void* d_ws, size_t ws_size,
                              hipStream_t stream) {
    const float* x = (const float*)d_in[0];
    float* out = (float*)d_out;
    const int threads = 256;
    const int total = N_ROWS / NPT;
    const int blocks = (total + threads - 1) / threads;
    fsq_kernel<<<blocks, threads, 0, stream>>>(x, out);
}